// Round 2
// baseline (811.427 us; speedup 1.0000x reference)
//
#include <hip/hip_runtime.h>

typedef unsigned short u16;
typedef unsigned int u32;
typedef __attribute__((ext_vector_type(8))) short short8;

#define DEV __device__ __forceinline__

DEV u16 f2bf(float f) {
  u32 u = __float_as_uint(f);
  u32 r = (u + 0x7fffu + ((u >> 16) & 1u)) >> 16;
  return (u16)r;
}
DEV float bf2f(u16 s) { return __uint_as_float(((u32)s) << 16); }

// ---------------------------------------------------------------------------
// K1: depthwise 3x3 conv, one output class-channel per blockIdx.y.
//   oc in [0,192): q = conv(x, w[oc])        -> qws[b*192+oc][n]
//   oc in [192,384): k = conv(y, w[oc])      -> kws[b*192+oc-192][n]
//   oc in [384,576): v = conv(y, w[oc])      -> vws[b*192+oc-384][n]
// block 256 = 16x16 pixels; each block does a 64x16 tile (4 row-steps).
// grid = dim3(128 = b*16 + tr2*8 + tc, 576)
// ---------------------------------------------------------------------------
__global__ __launch_bounds__(256) void k1_conv(
    const float* __restrict__ x, const float* __restrict__ y,
    const float* __restrict__ wdw,
    u16* __restrict__ qws, u16* __restrict__ kws, u16* __restrict__ vws)
{
  const int t   = threadIdx.x;
  const int gx  = blockIdx.x;
  const int oc  = blockIdx.y;            // 0..575
  const int b   = gx >> 4;
  const int tr2 = (gx >> 3) & 1;
  const int tc  = gx & 7;
  const int cls = oc / 192;              // 0=q,1=k,2=v
  const int cg  = oc % 192;              // global channel

  const float* __restrict__ in =
      (cls == 0 ? x : y) + (size_t)(b * 192 + cg) * 16384;

  float w[9];
#pragma unroll
  for (int i = 0; i < 9; ++i) w[i] = wdw[oc * 9 + i];

  u16* __restrict__ dst =
      (cls == 0 ? qws : (cls == 1 ? kws : vws)) + (size_t)(b * 192 + cg) * 16384;

  const int r_l  = t >> 4;
  const int c_l  = t & 15;
  const int cpix = tc * 16 + c_l;

  for (int rr = 0; rr < 4; ++rr) {
    const int r = tr2 * 64 + rr * 16 + r_l;
    float acc = 0.0f;
#pragma unroll
    for (int dr = 0; dr < 3; ++dr) {
#pragma unroll
      for (int dc = 0; dc < 3; ++dc) {
        const int ar = r - 1 + dr;
        const int ac = cpix - 1 + dc;
        if (ar >= 0 && ar < 128 && ac >= 0 && ac < 128)
          acc = fmaf(w[dr * 3 + dc], in[ar * 128 + ac], acc);
      }
    }
    dst[r * 128 + cpix] = f2bf(acc);
  }
}

// ---------------------------------------------------------------------------
// K2a: gram[bh][c][d] = sum_n q[bh][c][n]*k[bh][d][n]  (plain VALU, f32 acc)
// plus sum-of-squares for L2 norms. grid = 48 bh * 64 chunks of 256 n.
// Partials accumulated with f32 atomics into zeroed buffers.
// ---------------------------------------------------------------------------
__global__ __launch_bounds__(256) void k2a_gram(
    const u16* __restrict__ qws, const u16* __restrict__ kws,
    float* __restrict__ gram, float* __restrict__ sqq, float* __restrict__ sqk)
{
  __shared__ u16 qs[32][256];   // [c][j]
  __shared__ u16 kt[256][32];   // [j][d]  (transposed for conflict-free read)
  const int t  = threadIdx.x;
  const int bx = blockIdx.x;
  const int bh = bx >> 6;
  const int ck = bx & 63;
  const int n0 = ck * 256;
  const u16* __restrict__ qb = qws + ((size_t)bh << 19);  // bh*32*16384
  const u16* __restrict__ kb = kws + ((size_t)bh << 19);

#pragma unroll
  for (int i = 0; i < 4; ++i) {
    const int c = i * 8 + (t >> 5);
    const int j = (t & 31) * 8;
    short8 qv = *(const short8*)(qb + (size_t)c * 16384 + n0 + j);
    short8 kv = *(const short8*)(kb + (size_t)c * 16384 + n0 + j);
    *(short8*)&qs[c][j] = qv;
#pragma unroll
    for (int jj = 0; jj < 8; ++jj) kt[j + jj][c] = (u16)kv[jj];
  }
  __syncthreads();

#pragma unroll
  for (int p = 0; p < 4; ++p) {
    const int idx = p * 256 + t;
    const int c = idx >> 5, d = idx & 31;
    float a = 0.0f;
#pragma unroll 8
    for (int j = 0; j < 256; ++j)
      a = fmaf(bf2f(qs[c][j]), bf2f(kt[j][d]), a);
    atomicAdd(gram + (size_t)bh * 1024 + idx, a);   // idx == c*32+d
  }

  if (t < 32) {
    float a = 0.0f;
#pragma unroll 8
    for (int j = 0; j < 256; ++j) { float v = bf2f(qs[t][j]); a = fmaf(v, v, a); }
    atomicAdd(sqq + bh * 32 + t, a);
  } else if (t < 64) {
    const int d = t - 32;
    float a = 0.0f;
#pragma unroll 8
    for (int j = 0; j < 256; ++j) { float v = bf2f(kt[j][d]); a = fmaf(v, v, a); }
    atomicAdd(sqk + bh * 32 + d, a);
  }
}

// ---------------------------------------------------------------------------
// K2b: logits = gram/(|q||k|)*temp, row-softmax (over d), then fold 1x1 proj:
//   W2[b][o][h*32+d] = sum_c wp[o][h*32+c] * A[c][d]   (f32 out)
// one block per (b,h).
// ---------------------------------------------------------------------------
__global__ __launch_bounds__(256) void k2b_w2(
    const float* __restrict__ gram, const float* __restrict__ sqq,
    const float* __restrict__ sqk, const float* __restrict__ wp,
    const float* __restrict__ temp, float* __restrict__ W2)
{
  __shared__ float Ls[32][33];
  __shared__ float As[32][33];
  __shared__ float nq[32], nk[32];
  const int t  = threadIdx.x;
  const int bh = blockIdx.x, b = bh / 6, h = bh % 6;
  const float tmp = temp[h];
  if (t < 32) nq[t] = fmaxf(sqrtf(sqq[bh * 32 + t]), 1e-12f);
  if (t >= 32 && t < 64) nk[t - 32] = fmaxf(sqrtf(sqk[bh * 32 + t - 32]), 1e-12f);
  __syncthreads();
#pragma unroll
  for (int i = 0; i < 4; ++i) {
    const int idx = i * 256 + t, c = idx >> 5, d = idx & 31;
    Ls[c][d] = gram[(size_t)bh * 1024 + idx] / (nq[c] * nk[d]) * tmp;
  }
  __syncthreads();
  if (t < 32) {
    float m = -1e30f;
#pragma unroll
    for (int d = 0; d < 32; ++d) m = fmaxf(m, Ls[t][d]);
    float s = 0.0f;
#pragma unroll
    for (int d = 0; d < 32; ++d) s += expf(Ls[t][d] - m);
    const float inv = 1.0f / s;
#pragma unroll
    for (int d = 0; d < 32; ++d) As[t][d] = expf(Ls[t][d] - m) * inv;
  }
  __syncthreads();
  for (int i = 0; i < 24; ++i) {
    const int idx = i * 256 + t, o = idx >> 5, d = idx & 31;
    float a = 0.0f;
#pragma unroll
    for (int c = 0; c < 32; ++c)
      a = fmaf(wp[o * 192 + h * 32 + c], As[c][d], a);
    W2[((size_t)(b * 192 + o)) * 192 + h * 32 + d] = a;
  }
}

// ---------------------------------------------------------------------------
// K3: out[b][o][n] = sum_c W2[b][o][c] * v[b][c][n]   (plain VALU, f32)
// grid = dim3(64 n-tiles of 256, 96 = b*12 + o-group); block 256 (one n each).
// ---------------------------------------------------------------------------
__global__ __launch_bounds__(256) void k3_gemm(
    const float* __restrict__ W2, const u16* __restrict__ vws,
    float* __restrict__ out)
{
  __shared__ float W2l[16][192];
  const int t  = threadIdx.x;
  const int gy = blockIdx.y;
  const int b  = gy / 12, og = gy % 12;
  const int n  = blockIdx.x * 256 + t;

  for (int e = t; e < 16 * 192; e += 256) {
    const int o_l = e / 192, c = e % 192;
    W2l[o_l][c] = W2[((size_t)(b * 192 + og * 16 + o_l)) * 192 + c];
  }
  __syncthreads();

  float acc[16];
#pragma unroll
  for (int i = 0; i < 16; ++i) acc[i] = 0.0f;

  const u16* __restrict__ vb = vws + ((size_t)b * 192) * 16384;
  for (int c = 0; c < 192; ++c) {
    const float v = bf2f(vb[(size_t)c * 16384 + n]);
#pragma unroll
    for (int o_l = 0; o_l < 16; ++o_l)
      acc[o_l] = fmaf(W2l[o_l][c], v, acc[o_l]);
  }

  float* __restrict__ ob = out + ((size_t)b * 192 + og * 16) * 16384;
#pragma unroll
  for (int o_l = 0; o_l < 16; ++o_l)
    ob[(size_t)o_l * 16384 + n] = acc[o_l];
}

// ---------------------------------------------------------------------------
extern "C" void kernel_launch(void* const* d_in, const int* in_sizes, int n_in,
                              void* d_out, int out_size, void* d_ws, size_t ws_size,
                              hipStream_t stream)
{
  const float* x    = (const float*)d_in[0];
  const float* y    = (const float*)d_in[1];
  const float* wdw  = (const float*)d_in[2];
  const float* wp   = (const float*)d_in[3];
  const float* temp = (const float*)d_in[4];

  char* ws = (char*)d_ws;
  const size_t QK = (size_t)8 * 192 * 16384 * 2;   // 50,331,648 bytes per tensor
  u16*   qws  = (u16*)(ws);
  u16*   kws  = (u16*)(ws + QK);
  u16*   vws  = (u16*)(ws + 2 * QK);
  float* gram = (float*)(ws + 3 * QK);                 // 48*1024*4   = 196608
  float* sqq  = (float*)(ws + 3 * QK + 196608);        // 48*32*4     = 6144
  float* sqk  = (float*)(ws + 3 * QK + 196608 + 6144); // 48*32*4     = 6144
  float* W2   = (float*)(ws);   // overlays qws, written only after k2a is done
  float* out  = (float*)d_out;

  hipMemsetAsync(ws + 3 * QK, 0, 208896, stream);
  k1_conv<<<dim3(128, 576), 256, 0, stream>>>(x, y, wdw, qws, kws, vws);
  k2a_gram<<<3072, 256, 0, stream>>>(qws, kws, gram, sqq, sqk);
  k2b_w2<<<48, 256, 0, stream>>>(gram, sqq, sqk, wp, temp, W2);
  k3_gemm<<<dim3(64, 96), 256, 0, stream>>>(W2, vws, out);
}

// Round 3
// 230.222 us; speedup vs baseline: 3.5245x; 3.5245x over previous
//
#include <hip/hip_runtime.h>

#define DEV __device__ __forceinline__

typedef unsigned short u16;
typedef unsigned int u32;
typedef __attribute__((ext_vector_type(8))) short short8;
typedef __attribute__((ext_vector_type(4))) float f32x4;

DEV u16 f2bf(float f) {
  u32 u = __float_as_uint(f);
  u32 r = (u + 0x7fffu + ((u >> 16) & 1u)) >> 16;
  return (u16)r;
}
DEV float bf2f_s(short s) { return __uint_as_float(((u32)(u16)s) << 16); }

#define NB 8
#define NH 6
#define CH 32
#define CTOT 192
#define HW 16384

// ---------------------------------------------------------------------------
// K1: depthwise 3x3 conv. blockIdx.y==0: q from x -> qws[bh][c][n] (bf16)
//     blockIdx.y==1: k from y -> kws[bh][c][n]; v from y -> vt[b][n][gc]
//     (bf16, transposed via LDS so K3's MFMA B-fragments are 16B loads).
// block: 256 thr = 32 channels x 8 col-groups of 16 cols; 8 rows per block.
// FIX vs round 0: the vt_lds->global copy moves 16 u16 per thread (two
// short8), not 8 — previously half of vt was never written (the 0.31 absmax).
// ---------------------------------------------------------------------------
__global__ __launch_bounds__(256) void k1_conv(
    const float* __restrict__ x, const float* __restrict__ y,
    const float* __restrict__ wdw,
    u16* __restrict__ qws, u16* __restrict__ kws, u16* __restrict__ vt)
{
  const int t   = threadIdx.x;
  const int bx  = blockIdx.x;          // 768 = b*96 + cg*16 + rg
  const int typ = blockIdx.y;          // 0=q(x), 1=k+v(y)
  const int rg  = bx & 15;
  const int cg  = (bx >> 4) % 6;       // head
  const int b   = bx / 96;
  const int cl  = t >> 3;              // channel in head 0..31
  const int gc  = cg * 32 + cl;        // global channel
  const int p0  = (t & 7) * 16;        // col base
  const int r0  = rg * 8;

  const float* __restrict__ in = (typ == 0 ? x : y) + (((size_t)(b * CTOT + gc)) << 14);

  float wa[9], wb[9];
  if (typ == 0) {
#pragma unroll
    for (int i = 0; i < 9; ++i) wa[i] = wdw[gc * 9 + i];
  } else {
#pragma unroll
    for (int i = 0; i < 9; ++i) wa[i] = wdw[(CTOT + gc) * 9 + i];
#pragma unroll
    for (int i = 0; i < 9; ++i) wb[i] = wdw[(2 * CTOT + gc) * 9 + i];
  }

  __shared__ u16 vt_lds[128 * 32];

  u16* __restrict__ qkdst = (typ == 0 ? qws : kws) +
      (((size_t)((b * NH + cg) * CH + cl)) << 14);

  for (int rr = 0; rr < 8; ++rr) {
    const int r = r0 + rr;
    float rb[3][18];
#pragma unroll
    for (int dr = 0; dr < 3; ++dr) {
      const int ar = r - 1 + dr;
      const bool rok = (ar >= 0) && (ar < 128);
      const float* rp = in + ar * 128;
      rb[dr][0] = (rok && p0 > 0) ? rp[p0 - 1] : 0.0f;
#pragma unroll
      for (int k4 = 0; k4 < 4; ++k4) {
        float4 f;
        if (rok) f = *(const float4*)(rp + p0 + k4 * 4);
        else     f = make_float4(0.f, 0.f, 0.f, 0.f);
        rb[dr][1 + k4 * 4 + 0] = f.x;
        rb[dr][1 + k4 * 4 + 1] = f.y;
        rb[dr][1 + k4 * 4 + 2] = f.z;
        rb[dr][1 + k4 * 4 + 3] = f.w;
      }
      rb[dr][17] = (rok && (p0 + 16) < 128) ? rp[p0 + 16] : 0.0f;
    }

    short8 pq0, pq1;
    float vvals[16];
#pragma unroll
    for (int u = 0; u < 16; ++u) {
      float a = 0.f;
#pragma unroll
      for (int dr = 0; dr < 3; ++dr)
#pragma unroll
        for (int dc = 0; dc < 3; ++dc)
          a = fmaf(wa[dr * 3 + dc], rb[dr][u + dc], a);
      if (u < 8) pq0[u] = (short)f2bf(a); else pq1[u - 8] = (short)f2bf(a);
      if (typ) {
        float vv = 0.f;
#pragma unroll
        for (int dr = 0; dr < 3; ++dr)
#pragma unroll
          for (int dc = 0; dc < 3; ++dc)
            vv = fmaf(wb[dr * 3 + dc], rb[dr][u + dc], vv);
        vvals[u] = vv;
      }
    }
    *(short8*)(qkdst + r * 128 + p0)     = pq0;
    *(short8*)(qkdst + r * 128 + p0 + 8) = pq1;

    if (typ) {
#pragma unroll
      for (int u = 0; u < 16; ++u)
        vt_lds[(p0 + u) * 32 + cl] = f2bf(vvals[u]);
    }
    __syncthreads();
    if (typ) {
      // thread t owns pixel col = t>>1, channel half = (t&1)*16: 16 u16.
      short8 d0 = *(short8*)&vt_lds[t * 16];
      short8 d1 = *(short8*)&vt_lds[t * 16 + 8];
      const int col  = t >> 1;
      const int half = (t & 1) * 16;
      size_t off = ((size_t)(b * HW + r * 128 + col)) * CTOT + cg * 32 + half;
      *(short8*)(vt + off)     = d0;
      *(short8*)(vt + off + 8) = d1;
    }
    __syncthreads();
  }
}

// ---------------------------------------------------------------------------
// K2a: per (b,head): gram[c][d] = sum_n q[c][n]*k[d][n] via MFMA 16x16x32 bf16,
// plus sum-of-squares for the L2 norms. grid 48x16 p-tiles, partials via
// f32 atomics (zeroed by memset each launch).
// ---------------------------------------------------------------------------
__global__ __launch_bounds__(256) void k2a_gram(
    const u16* __restrict__ qws, const u16* __restrict__ kws,
    float* __restrict__ gram, float* __restrict__ sqq, float* __restrict__ sqk)
{
  const int t = threadIdx.x, l = t & 63, w = t >> 6;
  const int bh = blockIdx.x >> 4, tile = blockIdx.x & 15;
  const int p0 = tile * 1024 + w * 256;
  const u16* qb = qws + (((size_t)bh) << 19);
  const u16* kb = kws + (((size_t)bh) << 19);
  const int row = l & 15;
  const int kq  = (l >> 4) * 8;

  f32x4 acc[2][2] = {};
  float sq[2] = {0.f, 0.f}, sk[2] = {0.f, 0.f};

  for (int ks = 0; ks < 8; ++ks) {
    const int p = p0 + ks * 32 + kq;
    short8 av[2], bv[2];
#pragma unroll
    for (int tc = 0; tc < 2; ++tc) {
      av[tc] = *(const short8*)(qb + (((size_t)(tc * 16 + row)) << 14) + p);
      bv[tc] = *(const short8*)(kb + (((size_t)(tc * 16 + row)) << 14) + p);
    }
#pragma unroll
    for (int tc = 0; tc < 2; ++tc) {
#pragma unroll
      for (int j = 0; j < 8; ++j) {
        float fa = bf2f_s(av[tc][j]); sq[tc] = fmaf(fa, fa, sq[tc]);
        float fb = bf2f_s(bv[tc][j]); sk[tc] = fmaf(fb, fb, sk[tc]);
      }
    }
#pragma unroll
    for (int tc = 0; tc < 2; ++tc)
#pragma unroll
      for (int td = 0; td < 2; ++td)
        acc[tc][td] = __builtin_amdgcn_mfma_f32_16x16x32_bf16(av[tc], bv[td], acc[tc][td], 0, 0, 0);
  }

#pragma unroll
  for (int tc = 0; tc < 2; ++tc)
#pragma unroll
    for (int td = 0; td < 2; ++td)
#pragma unroll
      for (int rr = 0; rr < 4; ++rr) {
        int c = tc * 16 + (l >> 4) * 4 + rr;
        int d = td * 16 + row;
        atomicAdd(gram + (size_t)bh * 1024 + c * 32 + d, acc[tc][td][rr]);
      }

#pragma unroll
  for (int tc = 0; tc < 2; ++tc) {
    sq[tc] += __shfl_xor(sq[tc], 16);
    sq[tc] += __shfl_xor(sq[tc], 32);
    sk[tc] += __shfl_xor(sk[tc], 16);
    sk[tc] += __shfl_xor(sk[tc], 32);
  }
  if ((l >> 4) == 0) {
#pragma unroll
    for (int tc = 0; tc < 2; ++tc) {
      atomicAdd(sqq + bh * 32 + tc * 16 + row, sq[tc]);
      atomicAdd(sqk + bh * 32 + tc * 16 + row, sk[tc]);
    }
  }
}

// ---------------------------------------------------------------------------
// K2b: per (b,head): logits = gram/(|q||k|)*temp, softmax rows, then fold
// the projection: W2[b][o][h*32+d] = sum_c wp[o][h*32+c] * A[c][d]  (bf16 out)
// ---------------------------------------------------------------------------
__global__ __launch_bounds__(256) void k2b_w2(
    const float* __restrict__ gram, const float* __restrict__ sqq,
    const float* __restrict__ sqk, const float* __restrict__ wp,
    const float* __restrict__ temp, u16* __restrict__ W2)
{
  __shared__ float Ls[32][33];
  __shared__ float As[32][33];
  __shared__ float wl[192 * 32];
  __shared__ float nq[32], nk[32];
  const int t = threadIdx.x;
  const int bh = blockIdx.x, b = bh / 6, h = bh % 6;
  const float tmp = temp[h];
  if (t < 32) nq[t] = fmaxf(sqrtf(sqq[bh * 32 + t]), 1e-12f);
  else if (t < 64) nk[t - 32] = fmaxf(sqrtf(sqk[bh * 32 + t - 32]), 1e-12f);
  __syncthreads();
#pragma unroll
  for (int i = 0; i < 4; ++i) {
    int idx = i * 256 + t, c = idx >> 5, d = idx & 31;
    Ls[c][d] = gram[(size_t)bh * 1024 + idx] / (nq[c] * nk[d]) * tmp;
  }
  __syncthreads();
  if (t < 32) {
    float m = -1e30f;
#pragma unroll
    for (int d = 0; d < 32; ++d) m = fmaxf(m, Ls[t][d]);
    float s = 0.f;
#pragma unroll
    for (int d = 0; d < 32; ++d) s += expf(Ls[t][d] - m);
    float inv = 1.0f / s;
#pragma unroll
    for (int d = 0; d < 32; ++d) As[t][d] = expf(Ls[t][d] - m) * inv;
  }
  for (int i = 0; i < 24; ++i) {
    int idx = i * 256 + t, o = idx >> 5, c = idx & 31;
    wl[idx] = wp[o * 192 + h * 32 + c];
  }
  __syncthreads();
  for (int i = 0; i < 24; ++i) {
    int idx = i * 256 + t, o = idx >> 5, d = idx & 31;
    float a = 0.f;
#pragma unroll
    for (int c = 0; c < 32; ++c) a = fmaf(wl[o * 32 + c], As[c][d], a);
    W2[((size_t)(b * 192 + o)) * 192 + h * 32 + d] = f2bf(a);
  }
}

// ---------------------------------------------------------------------------
// K3: out[b][o][n] = sum_c W2[b][o][c] * v[b][c][n], via MFMA 16x16x32 bf16.
// A = W2 (row-major [o][c], k-contiguous), B = v_t (row-major [n][c],
// k-contiguous) -> every fragment is a direct 16B global load, no LDS.
// block: 256 thr = 4 waves; block tile 192o x 128n; wave: 12 o-tiles x 2 n-tiles.
// ---------------------------------------------------------------------------
__global__ __launch_bounds__(256) void k3_gemm(
    const u16* __restrict__ W2, const u16* __restrict__ vt,
    float* __restrict__ out)
{
  const int t = threadIdx.x, l = t & 63, w = t >> 6;
  const int bx = blockIdx.x;
  const int b  = bx >> 7, nb = bx & 127;
  const int row = l & 15;
  const int kq  = (l >> 4) * 8;
  const u16* w2b = W2 + (size_t)b * 192 * 192;
  const u16* vtb = vt + ((size_t)b << 14) * 192;
  const int n0 = nb * 128 + w * 32;

  f32x4 acc[12][2] = {};

  for (int ks = 0; ks < 6; ++ks) {
    const int kb = ks * 32 + kq;
    short8 bf[2];
#pragma unroll
    for (int nt = 0; nt < 2; ++nt)
      bf[nt] = *(const short8*)(vtb + (size_t)(n0 + nt * 16 + row) * 192 + kb);
#pragma unroll
    for (int ot = 0; ot < 12; ++ot) {
      short8 af = *(const short8*)(w2b + (size_t)(ot * 16 + row) * 192 + kb);
#pragma unroll
      for (int nt = 0; nt < 2; ++nt)
        acc[ot][nt] = __builtin_amdgcn_mfma_f32_16x16x32_bf16(af, bf[nt], acc[ot][nt], 0, 0, 0);
    }
  }

  float* ob = out + ((size_t)b * 192) * 16384;
#pragma unroll
  for (int ot = 0; ot < 12; ++ot)
#pragma unroll
    for (int nt = 0; nt < 2; ++nt)
#pragma unroll
      for (int rr = 0; rr < 4; ++rr) {
        int o = ot * 16 + (l >> 4) * 4 + rr;
        int n = n0 + nt * 16 + row;
        ob[(size_t)o * 16384 + n] = acc[ot][nt][rr];
      }
}

// ---------------------------------------------------------------------------
extern "C" void kernel_launch(void* const* d_in, const int* in_sizes, int n_in,
                              void* d_out, int out_size, void* d_ws, size_t ws_size,
                              hipStream_t stream)
{
  const float* x    = (const float*)d_in[0];
  const float* y    = (const float*)d_in[1];
  const float* wdw  = (const float*)d_in[2];
  const float* wp   = (const float*)d_in[3];
  const float* temp = (const float*)d_in[4];

  char* ws = (char*)d_ws;
  const size_t QK = (size_t)48 * 32 * 16384 * 2;   // 50,331,648 bytes
  u16*   qws  = (u16*)(ws);
  u16*   kws  = (u16*)(ws + QK);
  u16*   vt   = (u16*)(ws + 2 * QK);
  float* gram = (float*)(ws + 3 * QK);                       // 48*1024*4
  float* sqq  = (float*)(ws + 3 * QK + 196608);              // 48*32*4
  float* sqk  = (float*)(ws + 3 * QK + 196608 + 6144);
  u16*   W2   = (u16*)(ws + 3 * QK + 196608 + 12288);        // 8*192*192*2
  float* out  = (float*)d_out;

  hipMemsetAsync(ws + 3 * QK, 0, 208896, stream);
  k1_conv<<<dim3(768, 2), 256, 0, stream>>>(x, y, wdw, qws, kws, vt);
  k2a_gram<<<768, 256, 0, stream>>>(qws, kws, gram, sqq, sqk);
  k2b_w2<<<48, 256, 0, stream>>>(gram, sqq, sqk, wp, temp, W2);
  k3_gemm<<<1024, 256, 0, stream>>>(W2, vt, out);
}

// Round 4
// 229.201 us; speedup vs baseline: 3.5402x; 1.0045x over previous
//
#include <hip/hip_runtime.h>

#define DEV __device__ __forceinline__

typedef unsigned short u16;
typedef unsigned int u32;
typedef __attribute__((ext_vector_type(8))) short short8;
typedef __attribute__((ext_vector_type(4))) float f32x4;

DEV u16 f2bf(float f) {
  u32 u = __float_as_uint(f);
  u32 r = (u + 0x7fffu + ((u >> 16) & 1u)) >> 16;
  return (u16)r;
}
DEV float bf2f_s(short s) { return __uint_as_float(((u32)(u16)s) << 16); }

#define NB 8
#define NH 6
#define CTOT 192
#define HW 16384
#define QLD 136   // padded row stride (u16) for q/k LDS tiles: 272B -> banks spread

DEV void loadrow(float* d, const float* __restrict__ in, int ar, int p0) {
  const bool rok = (ar >= 0) && (ar < 128);
  const float* rp = in + ar * 128;
  d[0] = (rok && p0 > 0) ? rp[p0 - 1] : 0.0f;
#pragma unroll
  for (int k4 = 0; k4 < 4; ++k4) {
    float4 f;
    if (rok) f = *(const float4*)(rp + p0 + k4 * 4);
    else     f = make_float4(0.f, 0.f, 0.f, 0.f);
    d[1 + k4 * 4 + 0] = f.x;
    d[1 + k4 * 4 + 1] = f.y;
    d[1 + k4 * 4 + 2] = f.z;
    d[1 + k4 * 4 + 3] = f.w;
  }
  d[17] = (rok && (p0 + 16) < 128) ? rp[p0 + 16] : 0.0f;
}

// ---------------------------------------------------------------------------
// K1 (fused): per block = (b, head, 8-row stripe):
//   - depthwise 3x3 conv of q (from x), k,v (from y) for 32 ch x 128 cols
//   - q,k staged to padded LDS, per-row MFMA partial gram + sum-of-squares
//   - v transposed via LDS -> vt[b][n][gc] for K3's direct B-fragments
// Deletes the qws/kws HBM round-trip (200 MB) and the separate k2a kernel.
// ---------------------------------------------------------------------------
__global__ __launch_bounds__(256) void k1_fused(
    const float* __restrict__ x, const float* __restrict__ y,
    const float* __restrict__ wdw,
    u16* __restrict__ vt, float* __restrict__ gram,
    float* __restrict__ sqq, float* __restrict__ sqk)
{
  const int t  = threadIdx.x;
  const int bx = blockIdx.x;           // 768 = b*96 + cg*16 + rg
  const int rg = bx & 15;
  const int cg = (bx >> 4) % 6;        // head
  const int b  = bx / 96;
  const int cl = t >> 3;               // channel in head 0..31
  const int gc = cg * 32 + cl;         // global channel
  const int p0 = (t & 7) * 16;         // col base
  const int r0 = rg * 8;
  const int bh = b * NH + cg;

  const float* __restrict__ xin = x + (((size_t)(b * CTOT + gc)) << 14);
  const float* __restrict__ yin = y + (((size_t)(b * CTOT + gc)) << 14);

  float wq[9], wk[9], wv[9];
#pragma unroll
  for (int i = 0; i < 9; ++i) {
    wq[i] = wdw[gc * 9 + i];
    wk[i] = wdw[(CTOT + gc) * 9 + i];
    wv[i] = wdw[(2 * CTOT + gc) * 9 + i];
  }

  __shared__ __align__(16) u16 q_lds[32 * QLD];
  __shared__ __align__(16) u16 k_lds[32 * QLD];
  __shared__ __align__(16) u16 vt_lds[128 * 32];

  // MFMA lane roles (same verified mapping as the passing k2a)
  const int l    = t & 63;
  const int w    = t >> 6;
  const int arow = l & 15;
  const int koff = w * 32 + ((l >> 4) << 3);   // col offset within 128

  f32x4 acc[2][2] = {};
  float sq[2] = {0.f, 0.f}, sk[2] = {0.f, 0.f};

  for (int rr = 0; rr < 8; ++rr) {
    const int r = r0 + rr;
    float xw[3][18], yw[3][18];
#pragma unroll
    for (int dr = 0; dr < 3; ++dr) {
      loadrow(xw[dr], xin, r - 1 + dr, p0);
      loadrow(yw[dr], yin, r - 1 + dr, p0);
    }

    short8 pq0, pq1, pk0, pk1;
#pragma unroll
    for (int u = 0; u < 16; ++u) {
      float aq = 0.f, ak = 0.f, av = 0.f;
#pragma unroll
      for (int dr = 0; dr < 3; ++dr)
#pragma unroll
        for (int dc = 0; dc < 3; ++dc) {
          aq = fmaf(wq[dr * 3 + dc], xw[dr][u + dc], aq);
          ak = fmaf(wk[dr * 3 + dc], yw[dr][u + dc], ak);
          av = fmaf(wv[dr * 3 + dc], yw[dr][u + dc], av);
        }
      if (u < 8) { pq0[u] = (short)f2bf(aq); pk0[u] = (short)f2bf(ak); }
      else       { pq1[u - 8] = (short)f2bf(aq); pk1[u - 8] = (short)f2bf(ak); }
      vt_lds[(p0 + u) * 32 + cl] = f2bf(av);
    }
    *(short8*)&q_lds[cl * QLD + p0]     = pq0;
    *(short8*)&q_lds[cl * QLD + p0 + 8] = pq1;
    *(short8*)&k_lds[cl * QLD + p0]     = pk0;
    *(short8*)&k_lds[cl * QLD + p0 + 8] = pk1;

    __syncthreads();

    // gram partial via MFMA + sum-of-squares from the same fragments
    short8 av2[2], bv2[2];
#pragma unroll
    for (int tc = 0; tc < 2; ++tc) {
      av2[tc] = *(const short8*)&q_lds[(tc * 16 + arow) * QLD + koff];
      bv2[tc] = *(const short8*)&k_lds[(tc * 16 + arow) * QLD + koff];
    }
#pragma unroll
    for (int tc = 0; tc < 2; ++tc)
#pragma unroll
      for (int j = 0; j < 8; ++j) {
        float fa = bf2f_s(av2[tc][j]); sq[tc] = fmaf(fa, fa, sq[tc]);
        float fb = bf2f_s(bv2[tc][j]); sk[tc] = fmaf(fb, fb, sk[tc]);
      }
#pragma unroll
    for (int tc = 0; tc < 2; ++tc)
#pragma unroll
      for (int td = 0; td < 2; ++td)
        acc[tc][td] = __builtin_amdgcn_mfma_f32_16x16x32_bf16(av2[tc], bv2[td], acc[tc][td], 0, 0, 0);

    // vt store: thread t owns (col=t>>1, 16-channel half t&1)
    {
      short8 d0 = *(short8*)&vt_lds[t * 16];
      short8 d1 = *(short8*)&vt_lds[t * 16 + 8];
      const int col  = t >> 1;
      const int half = (t & 1) * 16;
      size_t off = ((size_t)(b * HW + r * 128 + col)) * CTOT + cg * 32 + half;
      *(short8*)(vt + off)     = d0;
      *(short8*)(vt + off + 8) = d1;
    }
    __syncthreads();
  }

  // epilogue: accumulate partial gram and norms
#pragma unroll
  for (int tc = 0; tc < 2; ++tc)
#pragma unroll
    for (int td = 0; td < 2; ++td)
#pragma unroll
      for (int r2 = 0; r2 < 4; ++r2) {
        int c = tc * 16 + (l >> 4) * 4 + r2;
        int d = td * 16 + arow;
        atomicAdd(gram + (size_t)bh * 1024 + c * 32 + d, acc[tc][td][r2]);
      }
#pragma unroll
  for (int tc = 0; tc < 2; ++tc) {
    sq[tc] += __shfl_xor(sq[tc], 16);
    sq[tc] += __shfl_xor(sq[tc], 32);
    sk[tc] += __shfl_xor(sk[tc], 16);
    sk[tc] += __shfl_xor(sk[tc], 32);
  }
  if ((l >> 4) == 0) {
#pragma unroll
    for (int tc = 0; tc < 2; ++tc) {
      atomicAdd(sqq + bh * 32 + tc * 16 + arow, sq[tc]);
      atomicAdd(sqk + bh * 32 + tc * 16 + arow, sk[tc]);
    }
  }
}

// ---------------------------------------------------------------------------
// K2b: logits = gram/(|q||k|)*temp, row-softmax, fold 1x1 proj:
//   W2[b][o][h*32+d] = sum_c wp[o][h*32+c] * A[c][d]  (bf16 out)
// ---------------------------------------------------------------------------
__global__ __launch_bounds__(256) void k2b_w2(
    const float* __restrict__ gram, const float* __restrict__ sqq,
    const float* __restrict__ sqk, const float* __restrict__ wp,
    const float* __restrict__ temp, u16* __restrict__ W2)
{
  __shared__ float Ls[32][33];
  __shared__ float As[32][33];
  __shared__ float wl[192 * 32];
  __shared__ float nq[32], nk[32];
  const int t = threadIdx.x;
  const int bh = blockIdx.x, b = bh / 6, h = bh % 6;
  const float tmp = temp[h];
  if (t < 32) nq[t] = fmaxf(sqrtf(sqq[bh * 32 + t]), 1e-12f);
  else if (t < 64) nk[t - 32] = fmaxf(sqrtf(sqk[bh * 32 + t - 32]), 1e-12f);
  __syncthreads();
#pragma unroll
  for (int i = 0; i < 4; ++i) {
    int idx = i * 256 + t, c = idx >> 5, d = idx & 31;
    Ls[c][d] = gram[(size_t)bh * 1024 + idx] / (nq[c] * nk[d]) * tmp;
  }
  __syncthreads();
  if (t < 32) {
    float m = -1e30f;
#pragma unroll
    for (int d = 0; d < 32; ++d) m = fmaxf(m, Ls[t][d]);
    float s = 0.f;
#pragma unroll
    for (int d = 0; d < 32; ++d) s += expf(Ls[t][d] - m);
    float inv = 1.0f / s;
#pragma unroll
    for (int d = 0; d < 32; ++d) As[t][d] = expf(Ls[t][d] - m) * inv;
  }
  for (int i = 0; i < 24; ++i) {
    int idx = i * 256 + t, o = idx >> 5, c = idx & 31;
    wl[idx] = wp[o * 192 + h * 32 + c];
  }
  __syncthreads();
  for (int i = 0; i < 24; ++i) {
    int idx = i * 256 + t, o = idx >> 5, d = idx & 31;
    float a = 0.f;
#pragma unroll
    for (int c = 0; c < 32; ++c) a = fmaf(wl[o * 32 + c], As[c][d], a);
    W2[((size_t)(b * 192 + o)) * 192 + h * 32 + d] = f2bf(a);
  }
}

// ---------------------------------------------------------------------------
// K3: out[b][o][n] = sum_c W2[b][o][c] * v[b][c][n] via MFMA 16x16x32 bf16.
// A = W2 [o][c] k-contiguous, B = vt [n][c] k-contiguous: direct 16B loads.
// ---------------------------------------------------------------------------
__global__ __launch_bounds__(256) void k3_gemm(
    const u16* __restrict__ W2, const u16* __restrict__ vt,
    float* __restrict__ out)
{
  const int t = threadIdx.x, l = t & 63, w = t >> 6;
  const int bx = blockIdx.x;
  const int b  = bx >> 7, nb = bx & 127;
  const int row = l & 15;
  const int kq  = (l >> 4) * 8;
  const u16* w2b = W2 + (size_t)b * 192 * 192;
  const u16* vtb = vt + ((size_t)b << 14) * 192;
  const int n0 = nb * 128 + w * 32;

  f32x4 acc[12][2] = {};

  for (int ks = 0; ks < 6; ++ks) {
    const int kb = ks * 32 + kq;
    short8 bf[2];
#pragma unroll
    for (int nt = 0; nt < 2; ++nt)
      bf[nt] = *(const short8*)(vtb + (size_t)(n0 + nt * 16 + row) * 192 + kb);
#pragma unroll
    for (int ot = 0; ot < 12; ++ot) {
      short8 af = *(const short8*)(w2b + (size_t)(ot * 16 + row) * 192 + kb);
#pragma unroll
      for (int nt = 0; nt < 2; ++nt)
        acc[ot][nt] = __builtin_amdgcn_mfma_f32_16x16x32_bf16(af, bf[nt], acc[ot][nt], 0, 0, 0);
    }
  }

  float* ob = out + ((size_t)b * 192) * 16384;
#pragma unroll
  for (int ot = 0; ot < 12; ++ot)
#pragma unroll
    for (int nt = 0; nt < 2; ++nt)
#pragma unroll
      for (int rr = 0; rr < 4; ++rr) {
        int o = ot * 16 + (l >> 4) * 4 + rr;
        int n = n0 + nt * 16 + row;
        ob[(size_t)o * 16384 + n] = acc[ot][nt][rr];
      }
}

// ---------------------------------------------------------------------------
extern "C" void kernel_launch(void* const* d_in, const int* in_sizes, int n_in,
                              void* d_out, int out_size, void* d_ws, size_t ws_size,
                              hipStream_t stream)
{
  const float* x    = (const float*)d_in[0];
  const float* y    = (const float*)d_in[1];
  const float* wdw  = (const float*)d_in[2];
  const float* wp   = (const float*)d_in[3];
  const float* temp = (const float*)d_in[4];

  char* ws = (char*)d_ws;
  const size_t VT = (size_t)NB * HW * CTOT * 2;   // 50,331,648 bytes
  u16*   vt   = (u16*)(ws);
  float* gram = (float*)(ws + VT);                       // 48*1024*4 = 196608
  float* sqq  = (float*)(ws + VT + 196608);              // 48*32*4   = 6144
  float* sqk  = (float*)(ws + VT + 196608 + 6144);       // 6144
  u16*   W2   = (u16*)(ws + VT + 196608 + 12288);        // 8*192*192*2
  float* out  = (float*)d_out;

  hipMemsetAsync(ws + VT, 0, 208896, stream);
  k1_fused<<<768, 256, 0, stream>>>(x, y, wdw, vt, gram, sqq, sqk);
  k2b_w2<<<48, 256, 0, stream>>>(gram, sqq, sqk, wp, temp, W2);
  k3_gemm<<<1024, 256, 0, stream>>>(W2, vt, out);
}